// Round 1
// baseline (368.622 us; speedup 1.0000x reference)
//
#include <hip/hip_runtime.h>

// HistogramOfFeaturesModel: B=4096 rows, F=16384 feats, BINS=128, OUT=64.
// One block per row; 1024 threads; each thread caches 16 floats in regs so
// x is read from HBM exactly once (256 MiB -> ~43 us floor at 6.3 TB/s).

#define BINS   128
#define FEAT   16384
#define NOUT   64
#define TPB    1024
#define NWAVE  (TPB / 64)          // 16 waves
#define PER_T  (FEAT / TPB)        // 16 floats per thread
#define NFEATS (2 * BINS + 1)      // 257

__global__ __launch_bounds__(TPB) void hist_row_kernel(
    const float* __restrict__ x,
    const float* __restrict__ W,
    const float* __restrict__ b,
    float* __restrict__ out)
{
    __shared__ unsigned int s_hist[NWAVE][BINS];   // per-wave histogram copies
    __shared__ float s_red[2 * NWAVE];
    __shared__ float s_counts[BINS];
    __shared__ float s_mm[2];

    const int row  = blockIdx.x;
    const int tid  = threadIdx.x;
    const int lane = tid & 63;
    const int wave = tid >> 6;

    // zero the histogram copies (16*128 = 2048 words, 2 per thread)
    #pragma unroll
    for (int i = tid; i < NWAVE * BINS; i += TPB)
        ((unsigned int*)s_hist)[i] = 0u;

    // ---- load row into registers (coalesced float4), track min/max ----
    const float4* xr = (const float4*)(x + (size_t)row * FEAT);
    float4 v[PER_T / 4];
    float mn = INFINITY, mx = -INFINITY;
    #pragma unroll
    for (int c = 0; c < PER_T / 4; ++c) {
        v[c] = xr[c * TPB + tid];
        mn = fminf(mn, fminf(fminf(v[c].x, v[c].y), fminf(v[c].z, v[c].w)));
        mx = fmaxf(mx, fmaxf(fmaxf(v[c].x, v[c].y), fmaxf(v[c].z, v[c].w)));
    }

    // ---- block min/max reduction ----
    #pragma unroll
    for (int off = 32; off > 0; off >>= 1) {
        mn = fminf(mn, __shfl_down(mn, off));
        mx = fmaxf(mx, __shfl_down(mx, off));
    }
    if (lane == 0) { s_red[wave] = mn; s_red[NWAVE + wave] = mx; }
    __syncthreads();
    if (tid == 0) {
        float m0 = s_red[0], m1 = s_red[NWAVE];
        #pragma unroll
        for (int i = 1; i < NWAVE; ++i) {
            m0 = fminf(m0, s_red[i]);
            m1 = fmaxf(m1, s_red[NWAVE + i]);
        }
        s_mm[0] = m0; s_mm[1] = m1;
    }
    __syncthreads();
    const float rmn   = s_mm[0];
    const float rmx   = s_mm[1];
    const float width = rmx - rmn;
    // exact reference arithmetic: BINS / where(width==0, 1, width)
    const float scale = (float)BINS / (width == 0.0f ? 1.0f : width);

    // ---- histogram from registers into this wave's LDS copy ----
    unsigned int* hw = s_hist[wave];
    #pragma unroll
    for (int c = 0; c < PER_T / 4; ++c) {
        const float vv[4] = {v[c].x, v[c].y, v[c].z, v[c].w};
        #pragma unroll
        for (int k = 0; k < 4; ++k) {
            int idx = (int)floorf((vv[k] - rmn) * scale);
            idx = idx < 0 ? 0 : (idx > BINS - 1 ? BINS - 1 : idx);
            atomicAdd(&hw[idx], 1u);
        }
    }
    __syncthreads();

    // ---- reduce the 16 copies; density normalize (sum is exactly FEAT) ----
    if (tid < BINS) {
        unsigned int s = 0;
        #pragma unroll
        for (int wv = 0; wv < NWAVE; ++wv) s += s_hist[wv][tid];
        s_counts[tid] = (float)s * (1.0f / (float)FEAT);
    }
    __syncthreads();

    // ---- fused epilogue: out[row][o] = feats . W[o] + b[o] ----
    // feats[j]       = counts[j]                       for j < 128
    // feats[128 + k] = rmn + (k/128)*width             for k = 0..128
    const int o   = tid >> 4;   // 0..63, 16 threads per output
    const int sub = tid & 15;
    float acc = 0.0f;
    const float* Wo = W + o * NFEATS;
    for (int j = sub; j < NFEATS; j += 16) {
        const float f = (j < BINS)
            ? s_counts[j]
            : rmn + (float)(j - BINS) * (1.0f / (float)BINS) * width;
        acc += f * Wo[j];
    }
    #pragma unroll
    for (int off = 8; off > 0; off >>= 1)
        acc += __shfl_down(acc, off, 16);
    if (sub == 0)
        out[(size_t)row * NOUT + o] = acc + b[o];
}

extern "C" void kernel_launch(void* const* d_in, const int* in_sizes, int n_in,
                              void* d_out, int out_size, void* d_ws, size_t ws_size,
                              hipStream_t stream) {
    const float* x = (const float*)d_in[0];   // [4096, 16384]
    const float* W = (const float*)d_in[1];   // [64, 257]
    const float* b = (const float*)d_in[2];   // [64]
    float* out = (float*)d_out;               // [4096, 64]

    hist_row_kernel<<<4096, TPB, 0, stream>>>(x, W, b, out);
}